// Round 5
// baseline (103.569 us; speedup 1.0000x reference)
//
#include <hip/hip_runtime.h>

#define BB 32
#define HH 512
#define WW 512
#define CC 3
#define KK 16
#define NE 19          // K + 3
#define KNL 16         // nonlinear kernel terms
#define NN (HH * WW)   // 262144
#define BPB 4          // batches per block
#define NCF (BB * 2 * NE) // 1216 coeff floats

// Pre-kernel: coeff[b][p][e] = sum_k (src[p][k] + off[b][p*K+k]) * L_inv[e][3+k]
__global__ __launch_bounds__(256) void coeff_kernel(
    const float* __restrict__ dest_offsets, // (B, 2K)
    const float* __restrict__ L_inv,        // (NE, NE)
    const float* __restrict__ src_pts,      // (2, K)
    float* __restrict__ cf)                 // (B, 2, NE)
{
    const int i = blockIdx.x * 256 + threadIdx.x;
    if (i >= NCF) return;
    const int b = i / (2 * NE);
    const int rem = i - b * (2 * NE);
    const int p = rem / NE;
    const int e = rem - p * NE;
    float acc = 0.0f;
    #pragma unroll
    for (int k = 0; k < KK; ++k) {
        const float d = src_pts[p * KK + k] + dest_offsets[b * 2 * KK + p * KK + k];
        acc = fmaf(d, L_inv[e * NE + 3 + k], acc);
    }
    cf[i] = acc;
}

__global__ __launch_bounds__(256) void tps_kernel(
    const float* __restrict__ image,        // (B,H,W,C)
    const float* __restrict__ right_mat,    // (NE, N)
    const float* __restrict__ cf,           // (B, 2, NE) in d_ws
    float* __restrict__ out)                // (B,H,W,C)
{
    const int tid = threadIdx.x;
    const int n = blockIdx.x * 256 + tid;
    const int b0 = blockIdx.y * BPB;

    // right_mat rows 0..2 are [1; x_t; y_t] — compute instead of load.
    const int col = n & (WW - 1);
    const int row = n >> 9;
    const float xt = fmaf((float)col, 2.0f / 511.0f, -1.0f);
    const float yt = fmaf((float)row, 2.0f / 511.0f, -1.0f);

    // Nonlinear right_mat rows (coalesced across lanes).
    float rm[KNL];
    #pragma unroll
    for (int e = 0; e < KNL; ++e)
        rm[e] = right_mat[(size_t)(e + 3) * NN + n];

    const float* __restrict__ cfb = cf + (size_t)b0 * 2 * NE; // block-uniform -> s_load

    // Phase A: per batch, coords/weights + issue all 4 corner loads (dwordx3).
    float wgt[BPB][4];
    float px[BPB][4][CC];
    #pragma unroll
    for (int bb = 0; bb < BPB; ++bb) {
        const float* c0 = cfb + bb * 2 * NE;  // p = 0 (x) coeffs
        const float* c1 = c0 + NE;            // p = 1 (y) coeffs
        float tx = fmaf(c0[1], xt, c0[0]);
        float ty = fmaf(c1[1], xt, c1[0]);
        tx = fmaf(c0[2], yt, tx);
        ty = fmaf(c1[2], yt, ty);
        #pragma unroll
        for (int e = 0; e < KNL; ++e) {
            tx = fmaf(c0[3 + e], rm[e], tx);
            ty = fmaf(c1[3 + e], rm[e], ty);
        }

        const float x = 0.5f * (tx + 1.0f) * (float)WW;
        const float y = 0.5f * (ty + 1.0f) * (float)HH;

        int x0 = (int)x;   // trunc toward zero, matches astype(int32)
        int x1 = x0 + 1;
        int y0 = (int)y;
        int y1 = y0 + 1;
        x0 = min(max(x0, 0), WW - 1);
        x1 = min(max(x1, 0), WW - 1);
        y0 = min(max(y0, 0), HH - 1);
        y1 = min(max(y1, 0), HH - 1);

        const float x0f = (float)x0, x1f = (float)x1;
        const float y0f = (float)y0, y1f = (float)y1;
        wgt[bb][0] = (x1f - x) * (y1f - y);  // pa
        wgt[bb][1] = (x1f - x) * (y - y0f);  // pb
        wgt[bb][2] = (x - x0f) * (y1f - y);  // pc
        wgt[bb][3] = (x - x0f) * (y - y0f);  // pd

        const float* img = image + (size_t)(b0 + bb) * NN * CC;
        __builtin_memcpy(px[bb][0], img + ((size_t)y0 * WW + x0) * CC, CC * sizeof(float));
        __builtin_memcpy(px[bb][1], img + ((size_t)y1 * WW + x0) * CC, CC * sizeof(float));
        __builtin_memcpy(px[bb][2], img + ((size_t)y0 * WW + x1) * CC, CC * sizeof(float));
        __builtin_memcpy(px[bb][3], img + ((size_t)y1 * WW + x1) * CC, CC * sizeof(float));
    }

    // Keep all 16 gathers issued (loads cannot be sunk across this).
    __builtin_amdgcn_sched_barrier(0);

    // Phase B: combine + store.
    float* __restrict__ o = out + ((size_t)b0 * NN + n) * CC;
    #pragma unroll
    for (int bb = 0; bb < BPB; ++bb) {
        float res[CC];
        #pragma unroll
        for (int c = 0; c < CC; ++c) {
            res[c] = wgt[bb][0] * px[bb][0][c] + wgt[bb][1] * px[bb][1][c]
                   + wgt[bb][2] * px[bb][2][c] + wgt[bb][3] * px[bb][3][c];
        }
        __builtin_memcpy(o + (size_t)bb * NN * CC, res, CC * sizeof(float));
    }
}

extern "C" void kernel_launch(void* const* d_in, const int* in_sizes, int n_in,
                              void* d_out, int out_size, void* d_ws, size_t ws_size,
                              hipStream_t stream) {
    const float* image        = (const float*)d_in[0];
    const float* dest_offsets = (const float*)d_in[1];
    const float* right_mat    = (const float*)d_in[2];
    const float* L_inv        = (const float*)d_in[3];
    const float* src_pts      = (const float*)d_in[4];
    float* out = (float*)d_out;
    float* cf  = (float*)d_ws;   // 1216 floats

    hipLaunchKernelGGL(coeff_kernel, dim3((NCF + 255) / 256), dim3(256), 0, stream,
                       dest_offsets, L_inv, src_pts, cf);
    hipLaunchKernelGGL(tps_kernel, dim3(NN / 256, BB / BPB), dim3(256), 0, stream,
                       image, right_mat, cf, out);
}